// Round 11
// baseline (78.201 us; speedup 1.0000x reference)
//
#include <hip/hip_runtime.h>
#include <hip/hip_bf16.h>
#include <math.h>

#define N_NODES 16384
#define B_MOL   1024

typedef __attribute__((ext_vector_type(8))) short short8v;
typedef __attribute__((ext_vector_type(4))) float f32x4;

static __device__ __forceinline__ unsigned short f2bf(float f) {
    unsigned int u = __float_as_uint(f);
    unsigned int r = (u + 0x7FFFu + ((u >> 16) & 1u)) >> 16;   // RNE
    return (unsigned short)r;
}
static __device__ __forceinline__ float bf2f(unsigned short h) {
    return __uint_as_float(((unsigned int)h) << 16);
}

// ---------------------------------------------------------------------------
// Pack all weights into MFMA-fragment order, bf16 hi/lo.
// Fragment = (colblk of 16 cols) x (kstep of 32 k): 512 shorts, lane-major:
//   lane = (kk>>3)*16 + (col&15), pos = kk&7.
// frag index = (cb*nK + ks)*2 + hl, each 512 shorts.
// Segments (short offsets): L0 (512x128) @0, L1 @131072, M1 (256x128) @262144,
// M2 (256x256) @327680.
// ---------------------------------------------------------------------------
__global__ __launch_bounds__(256)
void conv_pack(const float* __restrict__ Wl, const float* __restrict__ Wr,
               const float* __restrict__ g1, const float* __restrict__ g2,
               unsigned short* __restrict__ wpk) {
    int idx = blockIdx.x * 256 + threadIdx.x;
    if (idx >= 229376) return;
    float v; size_t base; int nK, k, col;
    if (idx < 131072) {                      // layers 0/1: 512 cols x 128 k
        int l = idx >> 16;
        int e = idx & 65535;
        k = e >> 9; col = e & 511;
        v = (col < 256) ? Wl[l * 32768 + k * 256 + col]
                        : Wr[l * 32768 + k * 256 + (col - 256)];
        base = (size_t)l * 131072; nK = 4;
    } else if (idx < 163840) {               // MLP1: 256 x 128
        int e = idx - 131072; k = e >> 8; col = e & 255;
        v = g1[k * 256 + col]; base = 262144; nK = 4;
    } else {                                 // MLP2: 256 x 256
        int e = idx - 163840; k = e >> 8; col = e & 255;
        v = g2[k * 256 + col]; base = 327680; nK = 8;
    }
    int cb = col >> 4, ci = col & 15, ks = k >> 5, kk = k & 31;
    int lane = ((kk >> 3) << 4) | ci;
    size_t fo = ((size_t)(cb * nK + ks) * 2) * 512 + lane * 8 + (kk & 7);
    unsigned short h = f2bf(v);
    wpk[base + fo] = h;
    wpk[base + fo + 512] = f2bf(v - bf2f(h));
}

// ---------------------------------------------------------------------------
// Wave-tile GEMM, 32 rows x (NCB*16) cols, K = NK*32. A pairs from LDS
// [32][264]; B from frag-packed global (register double-buffered).
// Split-bf16: acc += ah*bh + ah*bl + al*bh.
// NCB=1 keeps live VGPRs ~55 (fits the 64-VGPR cap of 1024-thread blocks).
// ---------------------------------------------------------------------------
template<int NK, int NCB>
static __device__ __forceinline__ void tile_gemm32(
        const short* __restrict__ Ah, const short* __restrict__ Al,
        const unsigned short* __restrict__ wv,
        f32x4 (&acc)[2][NCB], int lane) {
    int lr = lane & 15;
    int kq = (lane >> 4) * 8;
    short8v bc[NCB][2], bn[NCB][2];
    #pragma unroll
    for (int j = 0; j < NCB; ++j) {
        bc[j][0] = *(const short8v*)&wv[((j * NK + 0) * 2 + 0) * 512 + lane * 8];
        bc[j][1] = *(const short8v*)&wv[((j * NK + 0) * 2 + 1) * 512 + lane * 8];
    }
    #pragma unroll
    for (int ks = 0; ks < NK; ++ks) {
        if (ks + 1 < NK) {
            #pragma unroll
            for (int j = 0; j < NCB; ++j) {
                bn[j][0] = *(const short8v*)&wv[((j * NK + ks + 1) * 2 + 0) * 512 + lane * 8];
                bn[j][1] = *(const short8v*)&wv[((j * NK + ks + 1) * 2 + 1) * 512 + lane * 8];
            }
        }
        short8v ah[2], al[2];
        #pragma unroll
        for (int i = 0; i < 2; ++i) {
            int ro = (i * 16 + lr) * 264 + ks * 32 + kq;
            ah[i] = *(const short8v*)&Ah[ro];
            al[i] = *(const short8v*)&Al[ro];
        }
        #pragma unroll
        for (int i = 0; i < 2; ++i)
            #pragma unroll
            for (int j = 0; j < NCB; ++j) {
                acc[i][j] = __builtin_amdgcn_mfma_f32_16x16x32_bf16(ah[i], bc[j][0], acc[i][j], 0, 0, 0);
                acc[i][j] = __builtin_amdgcn_mfma_f32_16x16x32_bf16(ah[i], bc[j][1], acc[i][j], 0, 0, 0);
                acc[i][j] = __builtin_amdgcn_mfma_f32_16x16x32_bf16(al[i], bc[j][0], acc[i][j], 0, 0, 0);
            }
        if (ks + 1 < NK) {
            #pragma unroll
            for (int j = 0; j < NCB; ++j) { bc[j][0] = bn[j][0]; bc[j][1] = bn[j][1]; }
        }
    }
}

static __device__ __forceinline__ void pack_pair(f32x4 o, short4* ph, short4* pl) {
    unsigned short h0 = f2bf(o[0]), h1 = f2bf(o[1]), h2 = f2bf(o[2]), h3 = f2bf(o[3]);
    *ph = make_short4((short)h0, (short)h1, (short)h2, (short)h3);
    *pl = make_short4((short)f2bf(o[0] - bf2f(h0)), (short)f2bf(o[1] - bf2f(h1)),
                      (short)f2bf(o[2] - bf2f(h2)), (short)f2bf(o[3] - bf2f(h3)));
}

// ---------------------------------------------------------------------------
// Whole network, one block per 2 molecules (32 rows), 1024 threads (16 waves).
// LDS ~108 KB -> 1 block/CU. No spills (NCB=1 GEMM tiles); agg rotation
// se=(s+2cw)&15 -> 4-way (pigeonhole floor) instead of 8-way.
// ---------------------------------------------------------------------------
__global__ __launch_bounds__(1024)
void mega(const float* __restrict__ H, const unsigned short* __restrict__ wpk,
          const float* __restrict__ bl, const float* __restrict__ br,
          const float* __restrict__ att, const float* __restrict__ gbias,
          const float* __restrict__ gb1, const float* __restrict__ gb2,
          const float* __restrict__ gW3, const float* __restrict__ gb3,
          float* __restrict__ out) {
    __shared__ short sAh[32][264], sAl[32][264];
    __shared__ float sL[32][260], sR[32][260];
    __shared__ float sLog[2][32][20];
    __shared__ float sAtt[512];
    __shared__ float sg[32], ssc[32];

    int tid  = threadIdx.x;
    int lane = tid & 63;
    int w    = tid >> 6;                 // wave 0..15
    int lr   = lane & 15;
    int rowBase = blockIdx.x * 32;

    // ---- stage H -> bf16 hi/lo pairs; stage att ----
    {
        int r = tid >> 5, q = tid & 31;
        f32x4 v = *(const f32x4*)&H[(size_t)(rowBase + r) * 128 + q * 4];
        pack_pair(v, (short4*)&sAh[r][q * 4], (short4*)&sAl[r][q * 4]);
        if (tid < 512) sAtt[tid] = att[tid];
    }
    __syncthreads();

    // ================= 2 GAT layers =================
    for (int l = 0; l < 2; ++l) {
        // ---- xl|xr GEMM: wave w -> 32 cols as two NCB=1 passes ----
        {
            #pragma unroll
            for (int p = 0; p < 2; ++p) {
                f32x4 acc[2][1];
                acc[0][0] = (f32x4){0.f, 0.f, 0.f, 0.f};
                acc[1][0] = (f32x4){0.f, 0.f, 0.f, 0.f};
                // global col-block cb = w*2+p (uniform for xl and xr)
                tile_gemm32<4, 1>(&sAh[0][0], &sAl[0][0],
                                  wpk + (size_t)l * 131072 + ((size_t)w * 2 + p) * 4096,
                                  acc, lane);
                float* dst; int cbase; const float* bp;
                if (w < 8) { dst = &sL[0][0]; cbase = w * 32; bp = bl + l * 256; }
                else       { dst = &sR[0][0]; cbase = (w - 8) * 32; bp = br + l * 256; }
                int cl = cbase + p * 16 + lr;
                float bv = bp[cl];
                #pragma unroll
                for (int i = 0; i < 2; ++i) {
                    int row0 = i * 16 + (lane >> 4) * 4;
                    #pragma unroll
                    for (int t = 0; t < 4; ++t)
                        dst[(row0 + t) * 260 + cl] = acc[i][0][t] + bv;
                }
            }
        }
        __syncthreads();

        // ---- fused logits + softmax: thread = (m2, dh, s); full 128-ch dot,
        //      then 16-lane butterfly softmax over s; leaky(x,.2)=.6x+.4|x| ----
        {
            int m2l = tid >> 9;
            int rem = tid & 511;
            int dh  = rem >> 4;           // d*2 + h
            int s   = rem & 15;           // low 4 bits of lane
            int d   = dh >> 1, hh = dh & 1;
            const float* xrp = &sR[m2l * 16 + d][hh * 128];
            const float* xlp = &sL[m2l * 16 + s][hh * 128];
            const float* ap  = &sAtt[l * 256 + hh * 128];
            float ac = 0.f;
            #pragma unroll 8
            for (int c4 = 0; c4 < 32; ++c4) {
                f32x4 av = *(const f32x4*)&ap[c4 * 4];
                f32x4 xv = *(const f32x4*)&xlp[c4 * 4];
                f32x4 rv = *(const f32x4*)&xrp[c4 * 4];
                f32x4 e = xv + rv;
                ac += 0.6f * av[0] * e[0] + 0.4f * av[0] * fabsf(e[0])
                    + 0.6f * av[1] * e[1] + 0.4f * av[1] * fabsf(e[1])
                    + 0.6f * av[2] * e[2] + 0.4f * av[2] * fabsf(e[2])
                    + 0.6f * av[3] * e[3] + 0.4f * av[3] * fabsf(e[3]);
            }
            float mx = ac;
            #pragma unroll
            for (int off = 1; off < 16; off <<= 1)
                mx = fmaxf(mx, __shfl_xor(mx, off, 16));
            float e = expf(ac - mx);
            float den = e;
            #pragma unroll
            for (int off = 1; off < 16; off <<= 1)
                den += __shfl_xor(den, off, 16);
            sLog[m2l][dh][s] = e / den;
        }
        __syncthreads();

        // ---- aggregation: thread = (m2, d, cw32); se=(s+2cw)&15 -> 4-way ----
        {
            int m2a = tid >> 9;
            int rem = tid & 511;
            int d  = rem >> 5;
            int cw = rem & 31;
            f32x4 f0 = (f32x4){0.f, 0.f, 0.f, 0.f};
            #pragma unroll
            for (int hh = 0; hh < 2; ++hh) {
                const float* alr = &sLog[m2a][d * 2 + hh][0];
                #pragma unroll
                for (int s = 0; s < 16; ++s) {
                    int se = (s + 2 * cw) & 15;
                    f0 += alr[se] * *(const f32x4*)&sL[m2a * 16 + se][hh * 128 + cw * 4];
                }
            }
            f32x4 o = f0 * 0.5f + *(const f32x4*)&gbias[l * 128 + cw * 4];
            int row = m2a * 16 + d;
            pack_pair(o, (short4*)&sAh[row][cw * 4], (short4*)&sAl[row][cw * 4]);
            if (l == 1)
                *(f32x4*)&sR[row][128 + cw * 4] = o;   // stash fp32 X (xr dead)
        }
        __syncthreads();
    }

    // ================= gate MLP =================
    // MLP1: h1 = leaky(X@gW1+gb1, .01) -> pairs back into sAh/sAl
    {
        f32x4 acc[2][1];
        acc[0][0] = (f32x4){0.f, 0.f, 0.f, 0.f};
        acc[1][0] = (f32x4){0.f, 0.f, 0.f, 0.f};
        tile_gemm32<4, 1>(&sAh[0][0], &sAl[0][0],
                          wpk + 262144 + (size_t)w * 4096, acc, lane);
        __syncthreads();   // drain A reads before overwrite
        int cl = w * 16 + lr;
        float bv = gb1[cl];
        #pragma unroll
        for (int i = 0; i < 2; ++i) {
            int row0 = i * 16 + (lane >> 4) * 4;
            #pragma unroll
            for (int t = 0; t < 4; ++t) {
                float v = acc[i][0][t] + bv;
                v = v >= 0.f ? v : 0.01f * v;
                unsigned short h = f2bf(v);
                sAh[row0 + t][cl] = (short)h;
                sAl[row0 + t][cl] = (short)f2bf(v - bf2f(h));
            }
        }
    }
    __syncthreads();

    // MLP2: h2 = leaky(h1@gW2+gb2, .01) -> sL fp32 (sL dead after agg)
    {
        f32x4 acc[2][1];
        acc[0][0] = (f32x4){0.f, 0.f, 0.f, 0.f};
        acc[1][0] = (f32x4){0.f, 0.f, 0.f, 0.f};
        tile_gemm32<8, 1>(&sAh[0][0], &sAl[0][0],
                          wpk + 327680 + (size_t)w * 8192, acc, lane);
        int cl = w * 16 + lr;
        float bv = gb2[cl];
        #pragma unroll
        for (int i = 0; i < 2; ++i) {
            int row0 = i * 16 + (lane >> 4) * 4;
            #pragma unroll
            for (int t = 0; t < 4; ++t) {
                float v = acc[i][0][t] + bv;
                v = v >= 0.f ? v : 0.01f * v;
                sL[row0 + t][cl] = v;
            }
        }
    }
    __syncthreads();

    // ---- gate dot: g[row] = h2[row]·gW3 + gb3 (32 lanes x 8 ch) ----
    {
        int grow = tid >> 5, l32 = tid & 31;
        f32x4 h2a = *(const f32x4*)&sL[grow][l32 * 8];
        f32x4 h2b = *(const f32x4*)&sL[grow][l32 * 8 + 4];
        f32x4 w3a = *(const f32x4*)&gW3[l32 * 8];
        f32x4 w3b = *(const f32x4*)&gW3[l32 * 8 + 4];
        float p = h2a[0] * w3a[0] + h2a[1] * w3a[1] + h2a[2] * w3a[2] + h2a[3] * w3a[3]
                + h2b[0] * w3b[0] + h2b[1] * w3b[1] + h2b[2] * w3b[2] + h2b[3] * w3b[3];
        #pragma unroll
        for (int off = 16; off; off >>= 1) p += __shfl_down(p, off, 32);
        if (l32 == 0) sg[grow] = p + gb3[0];
    }
    __syncthreads();

    // ---- segment softmax (16-wide) + scores ----
    if (tid < 32) {
        float v = sg[tid];
        float mx = v;
        #pragma unroll
        for (int off = 8; off; off >>= 1) mx = fmaxf(mx, __shfl_xor(mx, off, 16));
        float e = expf(v - mx);
        float den = e;
        #pragma unroll
        for (int off = 8; off; off >>= 1) den += __shfl_xor(den, off, 16);
        float sc = e / den;
        ssc[tid] = sc;
        out[131072 + rowBase + tid] = sc;
    }
    __syncthreads();

    // ---- pool: h_pool[mol] = sum_s score[s]*X[s] (X in sR cols 128..255) ----
    if (tid < 256) {
        int cc = tid & 127;
        int mp = tid >> 7;
        float a = 0.f;
        #pragma unroll
        for (int s = 0; s < 16; ++s)
            a += ssc[mp * 16 + s] * sR[mp * 16 + s][128 + cc];
        out[(size_t)(blockIdx.x * 2 + mp) * 128 + cc] = a;
    }
}

// ---------------------------------------------------------------------------
extern "C" void kernel_launch(void* const* d_in, const int* in_sizes, int n_in,
                              void* d_out, int out_size, void* d_ws, size_t ws_size,
                              hipStream_t stream) {
    (void)in_sizes; (void)n_in; (void)out_size; (void)ws_size;
    const float* H        = (const float*)d_in[0];
    const float* Wl       = (const float*)d_in[4];
    const float* bl       = (const float*)d_in[5];
    const float* Wr       = (const float*)d_in[6];
    const float* br       = (const float*)d_in[7];
    const float* att      = (const float*)d_in[8];
    const float* gat_bias = (const float*)d_in[9];
    const float* gW1      = (const float*)d_in[10];
    const float* gb1      = (const float*)d_in[11];
    const float* gW2      = (const float*)d_in[12];
    const float* gb2      = (const float*)d_in[13];
    const float* gW3      = (const float*)d_in[14];
    const float* gb3      = (const float*)d_in[15];
    float* out = (float*)d_out;

    unsigned short* wpk = (unsigned short*)d_ws;   // 458752 shorts

    conv_pack<<<896, 256, 0, stream>>>(Wl, Wr, gW1, gW2, wpk);
    mega<<<B_MOL / 2, 1024, 0, stream>>>(H, wpk, bl, br, att, gat_bias,
                                         gb1, gb2, gW3, gb3, out);
}

// Round 12
// 72.900 us; speedup vs baseline: 1.0727x; 1.0727x over previous
//
#include <hip/hip_runtime.h>
#include <hip/hip_bf16.h>
#include <math.h>

#define N_NODES 16384
#define B_MOL   1024

typedef __attribute__((ext_vector_type(8))) short short8v;
typedef __attribute__((ext_vector_type(4))) float f32x4;

static __device__ __forceinline__ unsigned short f2bf(float f) {
    unsigned int u = __float_as_uint(f);
    unsigned int r = (u + 0x7FFFu + ((u >> 16) & 1u)) >> 16;   // RNE
    return (unsigned short)r;
}
static __device__ __forceinline__ float bf2f(unsigned short h) {
    return __uint_as_float(((unsigned int)h) << 16);
}

// ---------------------------------------------------------------------------
// Pack all weights into MFMA-fragment order, bf16 hi/lo.
// Fragment = (colblk of 16 cols) x (kstep of 32 k): 512 shorts, lane-major:
//   lane = (kk>>3)*16 + (col&15), pos = kk&7.
// frag index = (cb*nK + ks)*2 + hl, each 512 shorts.
// Segments (short offsets): L0 (512x128) @0, L1 @131072, M1 (256x128) @262144,
// M2 (256x256) @327680.
// ---------------------------------------------------------------------------
__global__ __launch_bounds__(256)
void conv_pack(const float* __restrict__ Wl, const float* __restrict__ Wr,
               const float* __restrict__ g1, const float* __restrict__ g2,
               unsigned short* __restrict__ wpk) {
    int idx = blockIdx.x * 256 + threadIdx.x;
    if (idx >= 229376) return;
    float v; size_t base; int nK, k, col;
    if (idx < 131072) {                      // layers 0/1: 512 cols x 128 k
        int l = idx >> 16;
        int e = idx & 65535;
        k = e >> 9; col = e & 511;
        v = (col < 256) ? Wl[l * 32768 + k * 256 + col]
                        : Wr[l * 32768 + k * 256 + (col - 256)];
        base = (size_t)l * 131072; nK = 4;
    } else if (idx < 163840) {               // MLP1: 256 x 128
        int e = idx - 131072; k = e >> 8; col = e & 255;
        v = g1[k * 256 + col]; base = 262144; nK = 4;
    } else {                                 // MLP2: 256 x 256
        int e = idx - 163840; k = e >> 8; col = e & 255;
        v = g2[k * 256 + col]; base = 327680; nK = 8;
    }
    int cb = col >> 4, ci = col & 15, ks = k >> 5, kk = k & 31;
    int lane = ((kk >> 3) << 4) | ci;
    size_t fo = ((size_t)(cb * nK + ks) * 2) * 512 + lane * 8 + (kk & 7);
    unsigned short h = f2bf(v);
    wpk[base + fo] = h;
    wpk[base + fo + 512] = f2bf(v - bf2f(h));
}

// ---------------------------------------------------------------------------
// Wave-tile GEMM, 32 rows x (NCB*16) cols, K = NK*32. A pairs from LDS
// [32][264]; B from frag-packed global (register double-buffered).
// Split-bf16: acc += ah*bh + ah*bl + al*bh.
// ---------------------------------------------------------------------------
template<int NK, int NCB>
static __device__ __forceinline__ void tile_gemm32(
        const short* __restrict__ Ah, const short* __restrict__ Al,
        const unsigned short* __restrict__ wv,
        f32x4 (&acc)[2][NCB], int lane) {
    int lr = lane & 15;
    int kq = (lane >> 4) * 8;
    short8v bc[NCB][2], bn[NCB][2];
    #pragma unroll
    for (int j = 0; j < NCB; ++j) {
        bc[j][0] = *(const short8v*)&wv[((j * NK + 0) * 2 + 0) * 512 + lane * 8];
        bc[j][1] = *(const short8v*)&wv[((j * NK + 0) * 2 + 1) * 512 + lane * 8];
    }
    #pragma unroll
    for (int ks = 0; ks < NK; ++ks) {
        if (ks + 1 < NK) {
            #pragma unroll
            for (int j = 0; j < NCB; ++j) {
                bn[j][0] = *(const short8v*)&wv[((j * NK + ks + 1) * 2 + 0) * 512 + lane * 8];
                bn[j][1] = *(const short8v*)&wv[((j * NK + ks + 1) * 2 + 1) * 512 + lane * 8];
            }
        }
        short8v ah[2], al[2];
        #pragma unroll
        for (int i = 0; i < 2; ++i) {
            int ro = (i * 16 + lr) * 264 + ks * 32 + kq;
            ah[i] = *(const short8v*)&Ah[ro];
            al[i] = *(const short8v*)&Al[ro];
        }
        #pragma unroll
        for (int i = 0; i < 2; ++i)
            #pragma unroll
            for (int j = 0; j < NCB; ++j) {
                acc[i][j] = __builtin_amdgcn_mfma_f32_16x16x32_bf16(ah[i], bc[j][0], acc[i][j], 0, 0, 0);
                acc[i][j] = __builtin_amdgcn_mfma_f32_16x16x32_bf16(ah[i], bc[j][1], acc[i][j], 0, 0, 0);
                acc[i][j] = __builtin_amdgcn_mfma_f32_16x16x32_bf16(al[i], bc[j][0], acc[i][j], 0, 0, 0);
            }
        if (ks + 1 < NK) {
            #pragma unroll
            for (int j = 0; j < NCB; ++j) { bc[j][0] = bn[j][0]; bc[j][1] = bn[j][1]; }
        }
    }
}

static __device__ __forceinline__ void pack_pair(f32x4 o, short4* ph, short4* pl) {
    unsigned short h0 = f2bf(o[0]), h1 = f2bf(o[1]), h2 = f2bf(o[2]), h3 = f2bf(o[3]);
    *ph = make_short4((short)h0, (short)h1, (short)h2, (short)h3);
    *pl = make_short4((short)f2bf(o[0] - bf2f(h0)), (short)f2bf(o[1] - bf2f(h1)),
                      (short)f2bf(o[2] - bf2f(h2)), (short)f2bf(o[3] - bf2f(h3)));
}

// ---------------------------------------------------------------------------
// Whole network, one block per 2 molecules (32 rows), 1024 threads (16 waves).
// LDS ~108 KB -> 1 block/CU. __launch_bounds__(1024, 4): min 4 waves/EU =
// exactly our 1 block -> 128-VGPR budget -> no spills (R10/R11 had 64 + spill).
// ---------------------------------------------------------------------------
__global__ __launch_bounds__(1024, 4)
void mega(const float* __restrict__ H, const unsigned short* __restrict__ wpk,
          const float* __restrict__ bl, const float* __restrict__ br,
          const float* __restrict__ att, const float* __restrict__ gbias,
          const float* __restrict__ gb1, const float* __restrict__ gb2,
          const float* __restrict__ gW3, const float* __restrict__ gb3,
          float* __restrict__ out) {
    __shared__ short sAh[32][264], sAl[32][264];
    __shared__ float sL[32][260], sR[32][260];
    __shared__ float sLog[2][32][20];
    __shared__ float sAtt[512];
    __shared__ float sg[32], ssc[32];

    int tid  = threadIdx.x;
    int lane = tid & 63;
    int w    = tid >> 6;                 // wave 0..15
    int lr   = lane & 15;
    int rowBase = blockIdx.x * 32;

    // ---- stage H -> bf16 hi/lo pairs; stage att ----
    {
        int r = tid >> 5, q = tid & 31;
        f32x4 v = *(const f32x4*)&H[(size_t)(rowBase + r) * 128 + q * 4];
        pack_pair(v, (short4*)&sAh[r][q * 4], (short4*)&sAl[r][q * 4]);
        if (tid < 512) sAtt[tid] = att[tid];
    }
    __syncthreads();

    // ================= 2 GAT layers =================
    for (int l = 0; l < 2; ++l) {
        // ---- xl|xr GEMM: wave w -> global cols [w*32, w*32+32) of [xl|xr] ----
        {
            f32x4 acc[2][2];
            #pragma unroll
            for (int i = 0; i < 2; ++i)
                #pragma unroll
                for (int j = 0; j < 2; ++j) acc[i][j] = (f32x4){0.f, 0.f, 0.f, 0.f};
            tile_gemm32<4, 2>(&sAh[0][0], &sAl[0][0],
                              wpk + (size_t)l * 131072 + (size_t)w * 8192, acc, lane);
            float* dst; int cbase; const float* bp;
            if (w < 8) { dst = &sL[0][0]; cbase = w * 32; bp = bl + l * 256; }
            else       { dst = &sR[0][0]; cbase = (w - 8) * 32; bp = br + l * 256; }
            #pragma unroll
            for (int i = 0; i < 2; ++i) {
                int row0 = i * 16 + (lane >> 4) * 4;
                #pragma unroll
                for (int j = 0; j < 2; ++j) {
                    int cl = cbase + j * 16 + lr;
                    float bv = bp[cl];
                    #pragma unroll
                    for (int t = 0; t < 4; ++t)
                        dst[(row0 + t) * 260 + cl] = acc[i][j][t] + bv;
                }
            }
        }
        __syncthreads();

        // ---- fused logits + softmax: thread = (m2, dh, s); full 128-ch dot,
        //      then 16-lane butterfly softmax over s; leaky(x,.2)=.6x+.4|x| ----
        {
            int m2l = tid >> 9;
            int rem = tid & 511;
            int dh  = rem >> 4;           // d*2 + h
            int s   = rem & 15;           // low 4 bits of lane
            int d   = dh >> 1, hh = dh & 1;
            const float* xrp = &sR[m2l * 16 + d][hh * 128];
            const float* xlp = &sL[m2l * 16 + s][hh * 128];
            const float* ap  = &sAtt[l * 256 + hh * 128];
            float ac = 0.f;
            #pragma unroll 8
            for (int c4 = 0; c4 < 32; ++c4) {
                f32x4 av = *(const f32x4*)&ap[c4 * 4];
                f32x4 xv = *(const f32x4*)&xlp[c4 * 4];
                f32x4 rv = *(const f32x4*)&xrp[c4 * 4];
                f32x4 e = xv + rv;
                ac += 0.6f * av[0] * e[0] + 0.4f * av[0] * fabsf(e[0])
                    + 0.6f * av[1] * e[1] + 0.4f * av[1] * fabsf(e[1])
                    + 0.6f * av[2] * e[2] + 0.4f * av[2] * fabsf(e[2])
                    + 0.6f * av[3] * e[3] + 0.4f * av[3] * fabsf(e[3]);
            }
            float mx = ac;
            #pragma unroll
            for (int off = 1; off < 16; off <<= 1)
                mx = fmaxf(mx, __shfl_xor(mx, off, 16));
            float e = expf(ac - mx);
            float den = e;
            #pragma unroll
            for (int off = 1; off < 16; off <<= 1)
                den += __shfl_xor(den, off, 16);
            sLog[m2l][dh][s] = e / den;
        }
        __syncthreads();

        // ---- aggregation: thread = (m2, d, cw32); se=(s+2cw)&15 -> 4-way ----
        {
            int m2a = tid >> 9;
            int rem = tid & 511;
            int d  = rem >> 5;
            int cw = rem & 31;
            f32x4 f0 = (f32x4){0.f, 0.f, 0.f, 0.f};
            #pragma unroll
            for (int hh = 0; hh < 2; ++hh) {
                const float* alr = &sLog[m2a][d * 2 + hh][0];
                #pragma unroll
                for (int s = 0; s < 16; ++s) {
                    int se = (s + 2 * cw) & 15;
                    f0 += alr[se] * *(const f32x4*)&sL[m2a * 16 + se][hh * 128 + cw * 4];
                }
            }
            f32x4 o = f0 * 0.5f + *(const f32x4*)&gbias[l * 128 + cw * 4];
            int row = m2a * 16 + d;
            pack_pair(o, (short4*)&sAh[row][cw * 4], (short4*)&sAl[row][cw * 4]);
            if (l == 1)
                *(f32x4*)&sR[row][128 + cw * 4] = o;   // stash fp32 X (xr dead)
        }
        __syncthreads();
    }

    // ================= gate MLP =================
    // MLP1: h1 = leaky(X@gW1+gb1, .01) -> pairs back into sAh/sAl
    {
        f32x4 acc[2][1];
        acc[0][0] = (f32x4){0.f, 0.f, 0.f, 0.f};
        acc[1][0] = (f32x4){0.f, 0.f, 0.f, 0.f};
        tile_gemm32<4, 1>(&sAh[0][0], &sAl[0][0],
                          wpk + 262144 + (size_t)w * 4096, acc, lane);
        __syncthreads();   // drain A reads before overwrite
        int cl = w * 16 + lr;
        float bv = gb1[cl];
        #pragma unroll
        for (int i = 0; i < 2; ++i) {
            int row0 = i * 16 + (lane >> 4) * 4;
            #pragma unroll
            for (int t = 0; t < 4; ++t) {
                float v = acc[i][0][t] + bv;
                v = v >= 0.f ? v : 0.01f * v;
                unsigned short h = f2bf(v);
                sAh[row0 + t][cl] = (short)h;
                sAl[row0 + t][cl] = (short)f2bf(v - bf2f(h));
            }
        }
    }
    __syncthreads();

    // MLP2: h2 = leaky(h1@gW2+gb2, .01) -> sL fp32 (sL dead after agg)
    {
        f32x4 acc[2][1];
        acc[0][0] = (f32x4){0.f, 0.f, 0.f, 0.f};
        acc[1][0] = (f32x4){0.f, 0.f, 0.f, 0.f};
        tile_gemm32<8, 1>(&sAh[0][0], &sAl[0][0],
                          wpk + 327680 + (size_t)w * 8192, acc, lane);
        int cl = w * 16 + lr;
        float bv = gb2[cl];
        #pragma unroll
        for (int i = 0; i < 2; ++i) {
            int row0 = i * 16 + (lane >> 4) * 4;
            #pragma unroll
            for (int t = 0; t < 4; ++t) {
                float v = acc[i][0][t] + bv;
                v = v >= 0.f ? v : 0.01f * v;
                sL[row0 + t][cl] = v;
            }
        }
    }
    __syncthreads();

    // ---- gate dot: g[row] = h2[row]·gW3 + gb3 (32 lanes x 8 ch) ----
    {
        int grow = tid >> 5, l32 = tid & 31;
        f32x4 h2a = *(const f32x4*)&sL[grow][l32 * 8];
        f32x4 h2b = *(const f32x4*)&sL[grow][l32 * 8 + 4];
        f32x4 w3a = *(const f32x4*)&gW3[l32 * 8];
        f32x4 w3b = *(const f32x4*)&gW3[l32 * 8 + 4];
        float p = h2a[0] * w3a[0] + h2a[1] * w3a[1] + h2a[2] * w3a[2] + h2a[3] * w3a[3]
                + h2b[0] * w3b[0] + h2b[1] * w3b[1] + h2b[2] * w3b[2] + h2b[3] * w3b[3];
        #pragma unroll
        for (int off = 16; off; off >>= 1) p += __shfl_down(p, off, 32);
        if (l32 == 0) sg[grow] = p + gb3[0];
    }
    __syncthreads();

    // ---- segment softmax (16-wide) + scores ----
    if (tid < 32) {
        float v = sg[tid];
        float mx = v;
        #pragma unroll
        for (int off = 8; off; off >>= 1) mx = fmaxf(mx, __shfl_xor(mx, off, 16));
        float e = expf(v - mx);
        float den = e;
        #pragma unroll
        for (int off = 8; off; off >>= 1) den += __shfl_xor(den, off, 16);
        float sc = e / den;
        ssc[tid] = sc;
        out[131072 + rowBase + tid] = sc;
    }
    __syncthreads();

    // ---- pool: h_pool[mol] = sum_s score[s]*X[s] (X in sR cols 128..255) ----
    if (tid < 256) {
        int cc = tid & 127;
        int mp = tid >> 7;
        float a = 0.f;
        #pragma unroll
        for (int s = 0; s < 16; ++s)
            a += ssc[mp * 16 + s] * sR[mp * 16 + s][128 + cc];
        out[(size_t)(blockIdx.x * 2 + mp) * 128 + cc] = a;
    }
}

// ---------------------------------------------------------------------------
extern "C" void kernel_launch(void* const* d_in, const int* in_sizes, int n_in,
                              void* d_out, int out_size, void* d_ws, size_t ws_size,
                              hipStream_t stream) {
    (void)in_sizes; (void)n_in; (void)out_size; (void)ws_size;
    const float* H        = (const float*)d_in[0];
    const float* Wl       = (const float*)d_in[4];
    const float* bl       = (const float*)d_in[5];
    const float* Wr       = (const float*)d_in[6];
    const float* br       = (const float*)d_in[7];
    const float* att      = (const float*)d_in[8];
    const float* gat_bias = (const float*)d_in[9];
    const float* gW1      = (const float*)d_in[10];
    const float* gb1      = (const float*)d_in[11];
    const float* gW2      = (const float*)d_in[12];
    const float* gb2      = (const float*)d_in[13];
    const float* gW3      = (const float*)d_in[14];
    const float* gb3      = (const float*)d_in[15];
    float* out = (float*)d_out;

    unsigned short* wpk = (unsigned short*)d_ws;   // 458752 shorts

    conv_pack<<<896, 256, 0, stream>>>(Wl, Wr, gW1, gW2, wpk);
    mega<<<B_MOL / 2, 1024, 0, stream>>>(H, wpk, bl, br, att, gat_bias,
                                         gb1, gb2, gW3, gb3, out);
}